// Round 3
// baseline (29.417 us; speedup 1.0000x reference)
//
#include <hip/hip_runtime.h>

#define H 512
#define W 512
#define RPW 8                 // output rows per wave
#define WPB 4                 // waves per block -> 32-row band per block

__global__ __launch_bounds__(256) void lvar_kernel(const float* __restrict__ x,
                                                   float* __restrict__ out) {
    const int lane = threadIdx.x;                 // 0..63, owns cols 8*lane..8*lane+7
    const int wv   = threadIdx.y;                 // 0..3
    const int img  = blockIdx.y;
    const int R    = blockIdx.x * (RPW * WPB) + wv * RPW;   // first output row
    const float* __restrict__ xim = x + (size_t)img * (H * W);
    float* __restrict__ oim = out + (size_t)img * (H * W);

    const int c8 = lane * 8;
    const int upLane = (lane + 63) & 63;          // left neighbor (col-8)
    const int dnLane = (lane + 1) & 63;           // right neighbor (col+8)

    float vs[8], vs2[8];                          // running 7-row column sums
    float ring[8][8];                             // rows R-3..R+2, then R+3, R+4

    #pragma unroll
    for (int c = 0; c < 8; ++c) { vs[c] = 0.f; vs2[c] = 0.f; }

    // ---- init: accumulate rows R-3 .. R+2 ----
    #pragma unroll
    for (int k = 0; k < 6; ++k) {
        const int gr = (R - 3 + k) & (H - 1);
        const float4* p = (const float4*)(xim + gr * W + c8);
        const float4 a = p[0], b = p[1];
        const float v[8] = {a.x, a.y, a.z, a.w, b.x, b.y, b.z, b.w};
        #pragma unroll
        for (int c = 0; c < 8; ++c) {
            ring[k][c] = v[c];
            vs[c] += v[c];
            vs2[c] = fmaf(v[c], v[c], vs2[c]);
        }
    }

    const float inv = 1.0f / 49.0f;

    // ---- 8 output rows, fully unrolled (all ring indices static) ----
    #pragma unroll
    for (int j = 0; j < 8; ++j) {
        // add new row R+3+j
        const int gr = (R + 3 + j) & (H - 1);
        const float4* p = (const float4*)(xim + gr * W + c8);
        const float4 a = p[0], b = p[1];
        const float nv[8] = {a.x, a.y, a.z, a.w, b.x, b.y, b.z, b.w};
        #pragma unroll
        for (int c = 0; c < 8; ++c) {
            vs[c] += nv[c];
            vs2[c] = fmaf(nv[c], nv[c], vs2[c]);
        }
        if (j < 2) {                               // only R+3, R+4 ever get subtracted
            #pragma unroll
            for (int c = 0; c < 8; ++c) ring[6 + j][c] = nv[c];
        }

        // halo: left neighbor's cols 5..7, right neighbor's cols 0..2 (wraps mod 512)
        float Lh[3], Rh[3], Lh2[3], Rh2[3];
        #pragma unroll
        for (int t = 0; t < 3; ++t) {
            Lh[t]  = __shfl(vs [5 + t], upLane);
            Lh2[t] = __shfl(vs2[5 + t], upLane);
            Rh[t]  = __shfl(vs [t],     dnLane);
            Rh2[t] = __shfl(vs2[t],     dnLane);
        }

        // 14-wide window, sliding 7-tap horizontal sums
        float Wn[14], W2[14];
        #pragma unroll
        for (int t = 0; t < 3; ++t) { Wn[t] = Lh[t];  W2[t] = Lh2[t]; }
        #pragma unroll
        for (int c = 0; c < 8; ++c) { Wn[3 + c] = vs[c]; W2[3 + c] = vs2[c]; }
        #pragma unroll
        for (int t = 0; t < 3; ++t) { Wn[11 + t] = Rh[t]; W2[11 + t] = Rh2[t]; }

        float res[8];
        float s  = Wn[0] + Wn[1] + Wn[2] + Wn[3] + Wn[4] + Wn[5] + Wn[6];
        float s2 = W2[0] + W2[1] + W2[2] + W2[3] + W2[4] + W2[5] + W2[6];
        {
            const float m = s * inv;
            res[0] = fmaf(-m, m, s2 * inv);
        }
        #pragma unroll
        for (int k = 1; k < 8; ++k) {
            s  += Wn[k + 6] - Wn[k - 1];
            s2 += W2[k + 6] - W2[k - 1];
            const float m = s * inv;
            res[k] = fmaf(-m, m, s2 * inv);
        }

        float4* q = (float4*)(oim + (R + j) * W + c8);
        q[0] = make_float4(res[0], res[1], res[2], res[3]);
        q[1] = make_float4(res[4], res[5], res[6], res[7]);

        // subtract old row R-3+j (static ring slot j)
        #pragma unroll
        for (int c = 0; c < 8; ++c) {
            const float o = ring[j][c];
            vs[c] -= o;
            vs2[c] = fmaf(-o, o, vs2[c]);
        }
    }
}

extern "C" void kernel_launch(void* const* d_in, const int* in_sizes, int n_in,
                              void* d_out, int out_size, void* d_ws, size_t ws_size,
                              hipStream_t stream) {
    const float* x = (const float*)d_in[0];
    float* out = (float*)d_out;
    const int nimg = in_sizes[0] / (H * W);       // 16*3 = 48
    dim3 grid(H / (RPW * WPB), nimg);             // (16, 48) = 768 blocks
    dim3 block(64, WPB);
    lvar_kernel<<<grid, block, 0, stream>>>(x, out);
}

// Round 4
// 28.809 us; speedup vs baseline: 1.0211x; 1.0211x over previous
//
#include <hip/hip_runtime.h>

#define H 512
#define W 512
#define TH 8            // output rows per block
#define TCW 256         // output cols per block
#define PH 14           // TH + 6 input rows per block
#define KP 264          // pair-columns in LDS: 4 halo | 256 | 4 halo/pad
#define PITCH 548       // dwords per LDS row: 548 % 32 == 4 -> chunk-pitch 137 == 1 (mod 8)

__global__ __launch_bounds__(256) void lvar_kernel(const float* __restrict__ x,
                                                   float* __restrict__ out) {
    __shared__ float lds[TH * PITCH];   // interleaved (vs, vs2) pairs; 17536 B

    const int tid = threadIdx.x;        // 0..255
    const int c0  = blockIdx.x * TCW;   // 0 or 256
    const int R   = blockIdx.y * TH;
    const size_t ioff = (size_t)blockIdx.z * (size_t)(H * W);
    const float* __restrict__ xim = x + ioff;
    float* __restrict__ oim = out + ioff;

    // ---- Phase A: vertical 7-row sliding sums; thread u owns pair-cols 2u, 2u+1 ----
    // LDS pair-col k <-> global col c0 - 4 + k (mod 512); pair k lives at dwords 2k, 2k+1.
    if (tid < KP / 2) {
        const int gc = (c0 - 4 + 2 * tid + W) & (W - 1);      // even -> float2-aligned
        const float* __restrict__ colp = xim + gc;
        float va[PH], vb[PH];
        #pragma unroll
        for (int i = 0; i < PH; ++i) {
            const int gr = (R - 3 + i + H) & (H - 1);
            const float2 f = *(const float2*)(colp + gr * W); // wave: 512B contiguous
            va[i] = f.x; vb[i] = f.y;
        }
        float sa = 0.f, qa = 0.f, sb = 0.f, qb = 0.f;
        #pragma unroll
        for (int i = 0; i < 7; ++i) {
            sa += va[i]; qa = fmaf(va[i], va[i], qa);
            sb += vb[i]; qb = fmaf(vb[i], vb[i], qb);
        }
        float* dst = lds + 4 * tid;                           // dwords 4u..4u+3
        *(float4*)dst = make_float4(sa, qa, sb, qb);          // row 0
        #pragma unroll
        for (int r = 1; r < TH; ++r) {
            const float na = va[r + 6], oa = va[r - 1];
            const float nb = vb[r + 6], ob = vb[r - 1];
            sa += na - oa;
            qa = fmaf(na, na, qa); qa = fmaf(-oa, oa, qa);
            sb += nb - ob;
            qb = fmaf(nb, nb, qb); qb = fmaf(-ob, ob, qb);
            *(float4*)(dst + r * PITCH) = make_float4(sa, qa, sb, qb);
        }
    }
    __syncthreads();

    // ---- Phase B: horizontal 7-tap from LDS; task = (row tid&7, seg tid>>3) ----
    const int r = tid & 7;
    const int s = tid >> 3;                                   // 0..31, 8 output cols each
    const float4* src = (const float4*)(lds + r * PITCH + 16 * s);
    float v[32];                                              // pair-cols 8s .. 8s+15
    #pragma unroll
    for (int j = 0; j < 8; ++j) {                             // 8 x ds_read_b128
        const float4 f = src[j];
        v[4*j+0] = f.x; v[4*j+1] = f.y; v[4*j+2] = f.z; v[4*j+3] = f.w;
    }
    // output o (global col c0+8s+o) = window over local pairs p = o+1 .. o+7
    float s1 = 0.f, s2 = 0.f;
    #pragma unroll
    for (int p = 1; p <= 7; ++p) { s1 += v[2*p]; s2 += v[2*p+1]; }
    const float inv = 1.0f / 49.0f;
    float res[8];
    { const float m = s1 * inv; res[0] = fmaf(-m, m, s2 * inv); }
    #pragma unroll
    for (int o = 1; o < 8; ++o) {
        s1 += v[2*(o+7)]     - v[2*o];
        s2 += v[2*(o+7) + 1] - v[2*o + 1];
        const float m = s1 * inv;
        res[o] = fmaf(-m, m, s2 * inv);
    }
    float4* q = (float4*)(oim + (R + r) * W + c0 + 8 * s);
    q[0] = make_float4(res[0], res[1], res[2], res[3]);
    q[1] = make_float4(res[4], res[5], res[6], res[7]);
}

extern "C" void kernel_launch(void* const* d_in, const int* in_sizes, int n_in,
                              void* d_out, int out_size, void* d_ws, size_t ws_size,
                              hipStream_t stream) {
    const float* x = (const float*)d_in[0];
    float* out = (float*)d_out;
    const int nimg = in_sizes[0] / (H * W);       // 16*3 = 48
    dim3 grid(W / TCW, H / TH, nimg);             // (2, 64, 48) = 6144 blocks
    dim3 block(256);
    lvar_kernel<<<grid, block, 0, stream>>>(x, out);
}

// Round 5
// 24.702 us; speedup vs baseline: 1.1908x; 1.1662x over previous
//
#include <hip/hip_runtime.h>

#define H 512
#define W 512

// Full-width wave: lane owns cols 8L..8L+7; circular col-halo via lane shuffle.
// Each wave produces 4 output rows (reads 10 input rows). 6144 waves total.
__global__ __launch_bounds__(256, 4) void lvar_kernel(const float* __restrict__ x,
                                                      float* __restrict__ out) {
    const int lane = threadIdx.x;                 // 0..63
    const int wv   = threadIdx.y;                 // 0..3
    // XCD-bijective swizzle: 1536 blocks = 8 XCDs x 192 contiguous
    const int bid = blockIdx.x;
    const int wg  = (bid & 7) * 192 + (bid >> 3);
    const int img  = wg >> 5;                     // 0..47
    const int band = wg & 31;                     // 16-row superband
    const int R    = band * 16 + wv * 4;          // this wave's first output row

    const float* __restrict__ xim = x + (size_t)img * (H * W);
    float* __restrict__ oim = out + (size_t)img * (H * W);
    const int c8 = lane * 8;
    const int upLane = (lane + 63) & 63;
    const int dnLane = (lane + 1) & 63;
    const float inv = 1.0f / 49.0f;

    float s[8], q[8];        // running 7-row vertical sums (x, x^2)
    float keep[3][8];        // rows R-3, R-2, R-1 (subtracted at steps 1..3)
    float v[8];

    #pragma unroll
    for (int c = 0; c < 8; ++c) { s[c] = 0.f; q[c] = 0.f; }

    // ---- init: rows R-3 .. R+3 ----
    #pragma unroll
    for (int k = 0; k < 7; ++k) {
        const int gr = (R - 3 + k) & (H - 1);
        const float4* p = (const float4*)(xim + gr * W + c8);
        const float4 a = p[0], b = p[1];
        v[0]=a.x; v[1]=a.y; v[2]=a.z; v[3]=a.w;
        v[4]=b.x; v[5]=b.y; v[6]=b.z; v[7]=b.w;
        #pragma unroll
        for (int c = 0; c < 8; ++c) {
            s[c] += v[c];
            q[c] = fmaf(v[c], v[c], q[c]);
            if (k <= 2) keep[k][c] = v[c];        // static: k is compile-time
        }
    }

    // ---- emit one output row from current (s,q) ----
    auto emit = [&](int r) {
        float Lh[3], Rh[3], Lq[3], Rq[3];
        #pragma unroll
        for (int t = 0; t < 3; ++t) {
            Lh[t] = __shfl(s[5 + t], upLane);
            Lq[t] = __shfl(q[5 + t], upLane);
            Rh[t] = __shfl(s[t], dnLane);
            Rq[t] = __shfl(q[t], dnLane);
        }
        float Wn[14], W2[14];
        #pragma unroll
        for (int t = 0; t < 3; ++t) { Wn[t] = Lh[t]; W2[t] = Lq[t]; }
        #pragma unroll
        for (int c = 0; c < 8; ++c) { Wn[3 + c] = s[c]; W2[3 + c] = q[c]; }
        #pragma unroll
        for (int t = 0; t < 3; ++t) { Wn[11 + t] = Rh[t]; W2[11 + t] = Rq[t]; }

        float res[8];
        float hs  = Wn[0] + Wn[1] + Wn[2] + Wn[3] + Wn[4] + Wn[5] + Wn[6];
        float hq  = W2[0] + W2[1] + W2[2] + W2[3] + W2[4] + W2[5] + W2[6];
        { const float m = hs * inv; res[0] = fmaf(-m, m, hq * inv); }
        #pragma unroll
        for (int k = 1; k < 8; ++k) {
            hs += Wn[k + 6] - Wn[k - 1];
            hq += W2[k + 6] - W2[k - 1];
            const float m = hs * inv;
            res[k] = fmaf(-m, m, hq * inv);
        }
        float4* qp = (float4*)(oim + r * W + c8);
        qp[0] = make_float4(res[0], res[1], res[2], res[3]);
        qp[1] = make_float4(res[4], res[5], res[6], res[7]);
    };

    emit(R);

    // ---- rows R+1..R+3: slide window down ----
    #pragma unroll
    for (int j = 1; j <= 3; ++j) {
        const int gr = (R + 3 + j) & (H - 1);
        const float4* p = (const float4*)(xim + gr * W + c8);
        const float4 a = p[0], b = p[1];
        v[0]=a.x; v[1]=a.y; v[2]=a.z; v[3]=a.w;
        v[4]=b.x; v[5]=b.y; v[6]=b.z; v[7]=b.w;
        #pragma unroll
        for (int c = 0; c < 8; ++c) {
            const float o = keep[j - 1][c];        // row R-4+j (static index)
            s[c] += v[c] - o;
            q[c] = fmaf(v[c], v[c], q[c]);
            q[c] = fmaf(-o, o, q[c]);
        }
        emit(R + j);
    }
}

extern "C" void kernel_launch(void* const* d_in, const int* in_sizes, int n_in,
                              void* d_out, int out_size, void* d_ws, size_t ws_size,
                              hipStream_t stream) {
    const float* x = (const float*)d_in[0];
    float* out = (float*)d_out;
    const int nimg = in_sizes[0] / (H * W);       // 48
    dim3 grid(nimg * 32);                          // 1536 blocks (8 | 1536)
    dim3 block(64, 4);
    lvar_kernel<<<grid, block, 0, stream>>>(x, out);
}

// Round 7
// 21.979 us; speedup vs baseline: 1.3384x; 1.1239x over previous
//
#include <hip/hip_runtime.h>

#define H 512
#define W 512

typedef float f32x4 __attribute__((ext_vector_type(4)));

// DPP wave rotates (GCN/CDNA). Convention check (per the canonical DPP scan
// idiom "v_add_f32 ... row_shr:1" which accumulates from LOWER lanes):
//   *_shr / *_ror move data toward HIGHER lane indices: dst[i] = src[i-1]
//   *_shl / *_rol move data toward LOWER  lane indices: dst[i] = src[i+1]
__device__ __forceinline__ float dpp_left1(float v) {   // dst[i] = src[(i-1) & 63]
    return __int_as_float(__builtin_amdgcn_update_dpp(
        0, __float_as_int(v), 0x13C /*wave_ror:1*/, 0xF, 0xF, false));
}
__device__ __forceinline__ float dpp_right1(float v) {  // dst[i] = src[(i+1) & 63]
    return __int_as_float(__builtin_amdgcn_update_dpp(
        0, __float_as_int(v), 0x134 /*wave_rol:1*/, 0xF, 0xF, false));
}

__global__ __launch_bounds__(256, 4) void lvar_kernel(const float* __restrict__ x,
                                                      float* __restrict__ out) {
    const int lane = threadIdx.x;                 // 0..63, owns cols 8*lane..8*lane+7
    const int wv   = threadIdx.y;                 // 0..3
    // XCD-bijective swizzle: 1536 blocks = 8 XCDs x 192 contiguous
    const int bid  = blockIdx.x;
    const int wg   = (bid & 7) * 192 + (bid >> 3);
    const int img  = wg >> 5;                     // 0..47
    const int band = wg & 31;
    const int R    = band * 16 + wv * 4;          // this wave's first output row

    const float* __restrict__ xim = x + (size_t)img * (H * W);
    float* __restrict__ oim = out + (size_t)img * (H * W);
    const int c8 = lane * 8;
    const float inv = 1.0f / 49.0f;

    float s[8], q[8];        // running 7-row vertical sums of x, x^2
    float keep[3][8];        // rows R-3..R-1, subtracted at steps 1..3

    #pragma unroll
    for (int c = 0; c < 8; ++c) { s[c] = 0.f; q[c] = 0.f; }

    auto loadrow = [&](int r, float v[8]) {
        const int gr = r & (H - 1);
        const f32x4* p = (const f32x4*)(xim + gr * W + c8);
        const f32x4 a = p[0], b = p[1];
        v[0]=a.x; v[1]=a.y; v[2]=a.z; v[3]=a.w;
        v[4]=b.x; v[5]=b.y; v[6]=b.z; v[7]=b.w;
    };

    auto emit = [&](int r) {
        float Wn[14], W2[14];
        #pragma unroll
        for (int t = 0; t < 3; ++t) {             // halo via DPP rotates (wrap mod 512)
            Wn[t]      = dpp_left1(s[5 + t]);     // left neighbor's cols 5..7
            W2[t]      = dpp_left1(q[5 + t]);
            Wn[11 + t] = dpp_right1(s[t]);        // right neighbor's cols 0..2
            W2[11 + t] = dpp_right1(q[t]);
        }
        #pragma unroll
        for (int c = 0; c < 8; ++c) { Wn[3 + c] = s[c]; W2[3 + c] = q[c]; }

        float res[8];
        float hs = Wn[0]+Wn[1]+Wn[2]+Wn[3]+Wn[4]+Wn[5]+Wn[6];
        float hq = W2[0]+W2[1]+W2[2]+W2[3]+W2[4]+W2[5]+W2[6];
        { const float m = hs * inv; res[0] = fmaf(-m, m, hq * inv); }
        #pragma unroll
        for (int k = 1; k < 8; ++k) {
            hs += Wn[k + 6] - Wn[k - 1];
            hq += W2[k + 6] - W2[k - 1];
            const float m = hs * inv;
            res[k] = fmaf(-m, m, hq * inv);
        }
        f32x4* qp = (f32x4*)(oim + r * W + c8);
        f32x4 o0 = {res[0], res[1], res[2], res[3]};
        f32x4 o1 = {res[4], res[5], res[6], res[7]};
        __builtin_nontemporal_store(o0, qp);      // write-once output: bypass caches
        __builtin_nontemporal_store(o1, qp + 1);
    };

    auto update = [&](const float nv[8], const float old[8]) {
        #pragma unroll
        for (int c = 0; c < 8; ++c) {
            s[c] += nv[c] - old[c];
            q[c] = fmaf(nv[c], nv[c], q[c]);
            q[c] = fmaf(-old[c], old[c], q[c]);
        }
    };

    // ---- init: rows R-3 .. R+3 ----
    #pragma unroll
    for (int k = 0; k < 3; ++k) {
        loadrow(R - 3 + k, keep[k]);
        #pragma unroll
        for (int c = 0; c < 8; ++c) {
            s[c] += keep[k][c];
            q[c] = fmaf(keep[k][c], keep[k][c], q[c]);
        }
    }
    float va[8], vb[8];
    #pragma unroll
    for (int k = 3; k < 7; ++k) {
        loadrow(R - 3 + k, va);
        #pragma unroll
        for (int c = 0; c < 8; ++c) {
            s[c] += va[c];
            q[c] = fmaf(va[c], va[c], q[c]);
        }
    }

    // ---- 4 output rows, loads pipelined one emit ahead ----
    loadrow(R + 4, va);
    emit(R);
    loadrow(R + 5, vb);
    update(va, keep[0]);
    emit(R + 1);
    loadrow(R + 6, va);
    update(vb, keep[1]);
    emit(R + 2);
    update(va, keep[2]);
    emit(R + 3);
}

extern "C" void kernel_launch(void* const* d_in, const int* in_sizes, int n_in,
                              void* d_out, int out_size, void* d_ws, size_t ws_size,
                              hipStream_t stream) {
    const float* x = (const float*)d_in[0];
    float* out = (float*)d_out;
    const int nimg = in_sizes[0] / (H * W);       // 48
    dim3 grid(nimg * 32);                         // 1536 blocks (8 | 1536)
    dim3 block(64, 4);
    lvar_kernel<<<grid, block, 0, stream>>>(x, out);
}